// Round 1
// baseline (23647.586 us; speedup 1.0000x reference)
//
#include <hip/hip_runtime.h>
#include <math.h>

#define TPB 256
#define EPS_VN 1e-6f
#define SLOPE_VN 0.2f
#define SLOPE_SCA 0.01f

struct PW {
  const float *g1_Wvh,*g1_Ws,*g1_Wvo,*g1_Wg,*g1_bg,*g1_Wd;
  const float *g2_Wvh,*g2_Ws,*g2_Wvo,*g2_Wg,*g2_bg;
  const float *a1_Wvh,*a1_Ws,*a1_Wvo,*a1_Wg,*a1_bg,*a1_Wd;
  const float *a2_Wvh,*a2_Ws,*a2_Wvo,*a2_Wg,*a2_bg,*a2_Wd;
  const float *f_Wvh,*f_Ws;
};

// vout[o][i] = sum_c W[o][c] * vin[c][i], optionally norm_out[o] = ||vout[o][:]||
__device__ __forceinline__ void mv3(const float* __restrict__ W, int O, int C,
                                    const float* vin, float* vout,
                                    float* norm_out) {
  const int t = threadIdx.x;
  const int C4 = C >> 2;
  for (int o = t; o < O; o += TPB) {
    const float4* Wr = (const float4*)(W + (size_t)o * C);
    float a0 = 0.f, a1 = 0.f, a2 = 0.f;
    #pragma unroll 4
    for (int c4 = 0; c4 < C4; ++c4) {
      float4 w = Wr[c4];
      const float* x = vin + c4 * 12;
      a0 += w.x * x[0] + w.y * x[3] + w.z * x[6] + w.w * x[9];
      a1 += w.x * x[1] + w.y * x[4] + w.z * x[7] + w.w * x[10];
      a2 += w.x * x[2] + w.y * x[5] + w.z * x[8] + w.w * x[11];
    }
    vout[o * 3 + 0] = a0;
    vout[o * 3 + 1] = a1;
    vout[o * 3 + 2] = a2;
    if (norm_out) norm_out[o] = sqrtf(a0 * a0 + a1 * a1 + a2 * a2);
  }
}

// out[o] = act(sum_c W[o][c] * xin[c] + bias[o]);  act: 0=none, 1=sigmoid
__device__ __forceinline__ void mvs(const float* __restrict__ W, int O, int C,
                                    const float* xin, float* out,
                                    const float* bias, int act) {
  const int t = threadIdx.x;
  const int C4 = C >> 2;
  for (int o = t; o < O; o += TPB) {
    const float4* Wr = (const float4*)(W + (size_t)o * C);
    float a = 0.f;
    #pragma unroll 4
    for (int c4 = 0; c4 < C4; ++c4) {
      float4 w = Wr[c4];
      const float* x = xin + c4 * 4;
      a += w.x * x[0] + w.y * x[1] + w.z * x[2] + w.w * x[3];
    }
    if (bias) a += bias[o];
    if (act == 1) a = 1.f / (1.f + expf(-a));
    out[o] = a;
  }
}

// x <- vn_leaky_relu(x) given precomputed d = Wd-matvec of x, both in LDS (O rows x 3)
__device__ __forceinline__ void vn_apply(float* x, const float* d, int O) {
  const int t = threadIdx.x;
  for (int o = t; o < O; o += TPB) {
    float x0 = x[o*3+0], x1 = x[o*3+1], x2 = x[o*3+2];
    float d0 = d[o*3+0], d1 = d[o*3+1], d2 = d[o*3+2];
    float dot = x0*d0 + x1*d1 + x2*d2;
    float dsq = d0*d0 + d1*d1 + d2*d2;
    float k = dot / (dsq + EPS_VN);
    // dot>=0: out = x; else out = SLOPE*x + (1-SLOPE)*(x - k*d)
    float n0 = SLOPE_VN * x0 + (1.f - SLOPE_VN) * (x0 - k * d0);
    float n1 = SLOPE_VN * x1 + (1.f - SLOPE_VN) * (x1 - k * d1);
    float n2 = SLOPE_VN * x2 + (1.f - SLOPE_VN) * (x2 - k * d2);
    bool pos = dot >= 0.f;
    x[o*3+0] = pos ? x0 : n0;
    x[o*3+1] = pos ? x1 : n1;
    x[o*3+2] = pos ? x2 : n2;
  }
}

__global__ __launch_bounds__(TPB) void pe_kernel(
    const float* __restrict__ h_sca, const float* __restrict__ h_vec,
    const float* __restrict__ pos_compose, const float* __restrict__ pos,
    PW W, const int* __restrict__ idx_focal, float* __restrict__ out, int F) {
  __shared__ float sv[256 * 3];    // current vector features (rows x 3)
  __shared__ float svh[256 * 3];   // vh
  __shared__ float sov[256 * 3];   // out_v / d scratch
  __shared__ float scat[384];      // [vnorm, sca] concat
  __shared__ float souts[256];     // out_s / reduction scratch
  __shared__ float sgate[256];     // gate
  __shared__ float ss[256];        // current scalar features
  __shared__ float srel[3];        // relpos

  const int e = blockIdx.x;
  if (e >= F) return;
  const int t = threadIdx.x;
  const int idx = idx_focal[e];

  // ---- gather ----
  ss[t] = h_sca[(size_t)idx * 256 + t];
  if (t < 192) sv[t] = h_vec[(size_t)idx * 192 + t];
  if (t < 3) srel[t] = pos[(size_t)e * 3 + t] - pos_compose[(size_t)idx * 3 + t];
  __syncthreads();

  // ================= g1: gv_perceptron =================
  mv3(W.g1_Wvh, 128, 64, sv, svh, scat);            // vh + vnorm -> scat[0:128]
  scat[128 + t] = ss[t];                            // cat = [vnorm, s]
  __syncthreads();
  mvs(W.g1_Ws, 128, 384, scat, souts, nullptr, 0);  // out_s
  __syncthreads();
  mv3(W.g1_Wvo, 128, 128, svh, sov, nullptr);       // out_v
  mvs(W.g1_Wg, 128, 128, souts, sgate, W.g1_bg, 1); // gate
  __syncthreads();
  for (int o = t; o < 128; o += TPB) {
    float g = sgate[o];
    sv[o*3+0] = g * sov[o*3+0];
    sv[o*3+1] = g * sov[o*3+1];
    sv[o*3+2] = g * sov[o*3+2];
    float x = souts[o];
    ss[o] = x >= 0.f ? x : SLOPE_SCA * x;           // leaky_relu on scalars
  }
  __syncthreads();
  mv3(W.g1_Wd, 128, 128, sv, sov, nullptr);         // d for vn_leaky
  __syncthreads();
  vn_apply(sv, sov, 128);
  __syncthreads();

  // ================= g2: gv_linear =================
  mv3(W.g2_Wvh, 128, 128, sv, svh, scat);
  if (t < 128) scat[128 + t] = ss[t];
  __syncthreads();
  mvs(W.g2_Ws, 128, 256, scat, souts, nullptr, 0);
  __syncthreads();
  mv3(W.g2_Wvo, 128, 128, svh, sov, nullptr);
  mvs(W.g2_Wg, 128, 128, souts, sgate, W.g2_bg, 1);
  __syncthreads();
  for (int o = t; o < 128; o += TPB) {
    float g = sgate[o];
    sv[o*3+0] = g * sov[o*3+0];
    sv[o*3+1] = g * sov[o*3+1];
    sv[o*3+2] = g * sov[o*3+2];
    ss[o] = souts[o];                               // no activation after g2
  }
  __syncthreads();

  // ================= a1: gv_perceptron =================
  mv3(W.a1_Wvh, 256, 128, sv, svh, scat);           // vnorm -> scat[0:256]
  if (t < 128) scat[256 + t] = ss[t];
  __syncthreads();
  mvs(W.a1_Ws, 128, 384, scat, souts, nullptr, 0);
  __syncthreads();
  mv3(W.a1_Wvo, 256, 256, svh, sov, nullptr);
  mvs(W.a1_Wg, 256, 128, souts, sgate, W.a1_bg, 1);
  __syncthreads();
  for (int o = t; o < 256; o += TPB) {
    float g = sgate[o];
    sv[o*3+0] = g * sov[o*3+0];
    sv[o*3+1] = g * sov[o*3+1];
    sv[o*3+2] = g * sov[o*3+2];
  }
  for (int o = t; o < 128; o += TPB) {
    float x = souts[o];
    ss[o] = x >= 0.f ? x : SLOPE_SCA * x;           // s_a1
  }
  __syncthreads();
  mv3(W.a1_Wd, 256, 256, sv, sov, nullptr);
  __syncthreads();
  vn_apply(sv, sov, 256);
  __syncthreads();

  // ---- mid: inner = <x_vec2, relpos>, s2 = [s_a1, inner] ----
  for (int h = t; h < 128; h += TPB) {
    const float* xr = sv + (128 + h) * 3;
    ss[128 + h] = xr[0] * srel[0] + xr[1] * srel[1] + xr[2] * srel[2];
  }
  __syncthreads();

  // ================= a2: gv_perceptron (v input = sv rows 0..127) =============
  mv3(W.a2_Wvh, 128, 128, sv, svh, scat);
  scat[128 + t] = ss[t];                            // s2 has 256 entries
  __syncthreads();
  mvs(W.a2_Ws, 128, 384, scat, souts, nullptr, 0);
  __syncthreads();
  mv3(W.a2_Wvo, 128, 128, svh, sov, nullptr);
  mvs(W.a2_Wg, 128, 128, souts, sgate, W.a2_bg, 1);
  __syncthreads();
  for (int o = t; o < 128; o += TPB) {
    float g = sgate[o];
    sv[o*3+0] = g * sov[o*3+0];
    sv[o*3+1] = g * sov[o*3+1];
    sv[o*3+2] = g * sov[o*3+2];
    float x = souts[o];
    ss[o] = x >= 0.f ? x : SLOPE_SCA * x;           // s_a2
  }
  __syncthreads();
  mv3(W.a2_Wd, 128, 128, sv, sov, nullptr);
  __syncthreads();
  vn_apply(sv, sov, 128);
  __syncthreads();

  // ================= f: gv_linear (scalar out only) =================
  mv3(W.f_Wvh, 128, 128, sv, svh, scat);
  if (t < 128) scat[128 + t] = ss[t];
  __syncthreads();
  // out = dot(f_Ws[0][0:256], scat[0:256])
  souts[t] = W.f_Ws[t] * scat[t];
  __syncthreads();
  for (int off = 128; off > 0; off >>= 1) {
    if (t < off) souts[t] += souts[t + off];
    __syncthreads();
  }
  if (t == 0) out[e] = souts[0];
}

extern "C" void kernel_launch(void* const* d_in, const int* in_sizes, int n_in,
                              void* d_out, int out_size, void* d_ws, size_t ws_size,
                              hipStream_t stream) {
  const float* h_sca       = (const float*)d_in[0];
  const float* h_vec       = (const float*)d_in[1];
  const float* pos_compose = (const float*)d_in[2];
  const float* pos         = (const float*)d_in[3];
  PW W;
  W.g1_Wvh = (const float*)d_in[4];
  W.g1_Ws  = (const float*)d_in[5];
  W.g1_Wvo = (const float*)d_in[6];
  W.g1_Wg  = (const float*)d_in[7];
  W.g1_bg  = (const float*)d_in[8];
  W.g1_Wd  = (const float*)d_in[9];
  W.g2_Wvh = (const float*)d_in[10];
  W.g2_Ws  = (const float*)d_in[11];
  W.g2_Wvo = (const float*)d_in[12];
  W.g2_Wg  = (const float*)d_in[13];
  W.g2_bg  = (const float*)d_in[14];
  W.a1_Wvh = (const float*)d_in[15];
  W.a1_Ws  = (const float*)d_in[16];
  W.a1_Wvo = (const float*)d_in[17];
  W.a1_Wg  = (const float*)d_in[18];
  W.a1_bg  = (const float*)d_in[19];
  W.a1_Wd  = (const float*)d_in[20];
  W.a2_Wvh = (const float*)d_in[21];
  W.a2_Ws  = (const float*)d_in[22];
  W.a2_Wvo = (const float*)d_in[23];
  W.a2_Wg  = (const float*)d_in[24];
  W.a2_bg  = (const float*)d_in[25];
  W.a2_Wd  = (const float*)d_in[26];
  W.f_Wvh  = (const float*)d_in[27];
  W.f_Ws   = (const float*)d_in[28];
  const int* idx_focal = (const int*)d_in[29];
  const int F = in_sizes[29];

  pe_kernel<<<dim3(F), dim3(TPB), 0, stream>>>(
      h_sca, h_vec, pos_compose, pos, W, idx_focal, (float*)d_out, F);
}

// Round 2
// 1177.160 us; speedup vs baseline: 20.0887x; 20.0887x over previous
//
#include <hip/hip_runtime.h>
#include <math.h>

#define TPB 256
#define E 16           // elements per block
#define VSTR 264       // [e][k] stride for vector-activation LDS buffers (f16)
#define SSTR 392       // scat stride
#define OSTR 136       // souts stride
#define SLOPE_VN 0.2f
#define SLOPE_SCA 0.01f
#define EPS_VN 1e-6f

using hfrag = __attribute__((ext_vector_type(8))) _Float16;
using h4    = __attribute__((ext_vector_type(4))) _Float16;
using ffrag = __attribute__((ext_vector_type(4))) float;

__device__ __forceinline__ ffrag mfma(hfrag a, hfrag b, ffrag c) {
  return __builtin_amdgcn_mfma_f32_16x16x32_f16(a, b, c, 0, 0, 0);
}

// ---- f16 weight pointers (into d_ws) ----
struct WB {
  const _Float16 *g1_Wvh,*g1_Ws,*g1_Wvo,*g1_Wg,*g1_Wd;
  const _Float16 *g2_Wvh,*g2_Ws,*g2_Wvo,*g2_Wg;
  const _Float16 *a1_Wvh,*a1_Ws,*a1_Wvo,*a1_Wg,*a1_Wd;
  const _Float16 *a2_Wvh,*a2_Ws,*a2_Wvo,*a2_Wg,*a2_Wd;
  const _Float16 *f_Wvh;
  const float *g1_bg,*g2_bg,*a1_bg,*a2_bg,*f_Ws;
};

// ---- weight f32->f16 conversion pre-pass ----
struct CvtJobs { const float* src[20]; _Float16* dst[20]; int n[20]; };

__global__ void cvt_kernel(CvtJobs J) {
  const int j = blockIdx.y;
  const float* __restrict__ s = J.src[j];
  _Float16* __restrict__ d = J.dst[j];
  const int n = J.n[j];
  for (int i = blockIdx.x * blockDim.x + threadIdx.x; i < n;
       i += gridDim.x * blockDim.x)
    d[i] = (_Float16)s[i];
}

// ---- GEMM helpers ----
// Vector GEMM: acc[t][c] += W[O][C] * v_c, tiles = wave + 4*t.
template<int TT, int KS>
__device__ __forceinline__ void gemmV(const _Float16* __restrict__ W, int C,
                                      const _Float16* vb, ffrag acc[TT][3]) {
  const int m = threadIdx.x & 15;
  const int q = (threadIdx.x >> 4) & 3;
  const int w = threadIdx.x >> 6;
  #pragma unroll
  for (int ks = 0; ks < KS; ++ks) {
    const int k = ks * 32 + q * 8;
    hfrag b0 = *(const hfrag*)(vb + 0 * E * VSTR + m * VSTR + k);
    hfrag b1 = *(const hfrag*)(vb + 1 * E * VSTR + m * VSTR + k);
    hfrag b2 = *(const hfrag*)(vb + 2 * E * VSTR + m * VSTR + k);
    #pragma unroll
    for (int t = 0; t < TT; ++t) {
      const int row = (w + t * 4) * 16 + m;
      hfrag a = *(const hfrag*)(W + (size_t)row * C + k);
      acc[t][0] = mfma(a, b0, acc[t][0]);
      acc[t][1] = mfma(a, b1, acc[t][1]);
      acc[t][2] = mfma(a, b2, acc[t][2]);
    }
  }
}

// Scalar GEMM: acc[t] += W[O][C] * s
template<int TT, int KS>
__device__ __forceinline__ void gemmS(const _Float16* __restrict__ W, int C,
                                      const _Float16* sb, int sstr, ffrag acc[TT]) {
  const int m = threadIdx.x & 15;
  const int q = (threadIdx.x >> 4) & 3;
  const int w = threadIdx.x >> 6;
  #pragma unroll
  for (int ks = 0; ks < KS; ++ks) {
    const int k = ks * 32 + q * 8;
    hfrag b = *(const hfrag*)(sb + m * sstr + k);
    #pragma unroll
    for (int t = 0; t < TT; ++t) {
      const int row = (w + t * 4) * 16 + m;
      hfrag a = *(const hfrag*)(W + (size_t)row * C + k);
      acc[t] = mfma(a, b, acc[t]);
    }
  }
}

// Store a C/D fragment into an [e][k] LDS buffer (4 consecutive k = rows).
__device__ __forceinline__ void stCD(_Float16* buf, int stride, int tile, ffrag v) {
  const int e = threadIdx.x & 15;
  const int q = (threadIdx.x >> 4) & 3;
  h4 p;
  p[0] = (_Float16)v[0]; p[1] = (_Float16)v[1];
  p[2] = (_Float16)v[2]; p[3] = (_Float16)v[3];
  *(h4*)(buf + e * stride + tile * 16 + q * 4) = p;
}

__device__ __forceinline__ float sigm(float x) { return 1.f / (1.f + expf(-x)); }

__global__ __launch_bounds__(TPB, 2) void pe_kernel(
    const float* __restrict__ h_sca, const float* __restrict__ h_vec,
    const float* __restrict__ pos_compose, const float* __restrict__ pos,
    WB W, const int* __restrict__ idx_focal, float* __restrict__ out, int F) {
  __shared__ _Float16 sv [3 * E * VSTR];  // current vector features, [comp][e][k]
  __shared__ _Float16 svh[3 * E * VSTR];  // vh
  __shared__ _Float16 scat[E * SSTR];     // [vnorm | s | inner] per element
  __shared__ _Float16 souts[E * OSTR];    // raw out_s
  __shared__ float srel[E * 3];

  const int t = threadIdx.x;
  const int wv = t >> 6;
  const int q = (t >> 4) & 3;
  const int el = t >> 4;     // gather: element handled by 16 threads
  const int c0 = t & 15;
  const int eg = blockIdx.x * E + el;

  // ======== gather (f32 -> f16 LDS) ========
  {
    const int idx = (eg < F) ? idx_focal[eg] : 0;
    for (int c = c0; c < 64; c += 16) {
      const float* p = h_vec + (size_t)idx * 192 + c * 3;
      sv[0 * E * VSTR + el * VSTR + c] = (_Float16)p[0];
      sv[1 * E * VSTR + el * VSTR + c] = (_Float16)p[1];
      sv[2 * E * VSTR + el * VSTR + c] = (_Float16)p[2];
    }
    for (int c = c0; c < 256; c += 16)
      scat[el * SSTR + 128 + c] = (_Float16)h_sca[(size_t)idx * 256 + c];
    if (c0 < 3 && eg < F)
      srel[el * 3 + c0] = pos[(size_t)eg * 3 + c0] - pos_compose[(size_t)idx * 3 + c0];
  }
  __syncthreads();

  ffrag zero = {0.f, 0.f, 0.f, 0.f};

  // ================= g1: perceptron (C=64 -> H=128 -> O=128) =================
  {
    ffrag vh[2][3];
    #pragma unroll
    for (int i = 0; i < 2; ++i) for (int c = 0; c < 3; ++c) vh[i][c] = zero;
    gemmV<2, 2>(W.g1_Wvh, 64, sv, vh);
    #pragma unroll
    for (int i = 0; i < 2; ++i) {
      const int tile = wv + i * 4;
      for (int c = 0; c < 3; ++c) stCD(svh + c * E * VSTR, VSTR, tile, vh[i][c]);
      ffrag n;
      #pragma unroll
      for (int r = 0; r < 4; ++r)
        n[r] = sqrtf(vh[i][0][r]*vh[i][0][r] + vh[i][1][r]*vh[i][1][r] + vh[i][2][r]*vh[i][2][r]);
      stCD(scat, SSTR, tile, n);   // vnorm -> scat[0:128]
    }
    __syncthreads();

    ffrag so[2]; so[0] = zero; so[1] = zero;
    gemmS<2, 12>(W.g1_Ws, 384, scat, SSTR, so);
    __syncthreads();               // all scat reads done
    #pragma unroll
    for (int i = 0; i < 2; ++i) {
      stCD(souts, OSTR, wv + i * 4, so[i]);           // raw out_s
      ffrag l;
      for (int r = 0; r < 4; ++r) { float x = so[i][r]; l[r] = x >= 0.f ? x : SLOPE_SCA * x; }
      stCD(scat + 128, SSTR, wv + i * 4, l);          // s for g2 at [128:256]
    }
    __syncthreads();

    ffrag ov[2][3]; ffrag g[2];
    #pragma unroll
    for (int i = 0; i < 2; ++i) { g[i] = zero; for (int c = 0; c < 3; ++c) ov[i][c] = zero; }
    gemmV<2, 4>(W.g1_Wvo, 128, svh, ov);
    gemmS<2, 4>(W.g1_Wg, 128, souts, OSTR, g);
    #pragma unroll
    for (int i = 0; i < 2; ++i) {
      const int tile = wv + i * 4;
      const float4 b = *(const float4*)(W.g1_bg + tile * 16 + q * 4);
      const float bb[4] = {b.x, b.y, b.z, b.w};
      #pragma unroll
      for (int r = 0; r < 4; ++r) {
        float gg = sigm(g[i][r] + bb[r]);
        ov[i][0][r] *= gg; ov[i][1][r] *= gg; ov[i][2][r] *= gg;
      }
      for (int c = 0; c < 3; ++c) stCD(sv + c * E * VSTR, VSTR, tile, ov[i][c]);
    }
    __syncthreads();               // v_new visible

    ffrag d[2][3];
    #pragma unroll
    for (int i = 0; i < 2; ++i) for (int c = 0; c < 3; ++c) d[i][c] = zero;
    gemmV<2, 4>(W.g1_Wd, 128, sv, d);
    __syncthreads();               // all v_new reads done
    #pragma unroll
    for (int i = 0; i < 2; ++i) {
      #pragma unroll
      for (int r = 0; r < 4; ++r) {
        float x0 = ov[i][0][r], x1 = ov[i][1][r], x2 = ov[i][2][r];
        float d0 = d[i][0][r],  d1 = d[i][1][r],  d2 = d[i][2][r];
        float dot = x0*d0 + x1*d1 + x2*d2;
        float kk = dot / (d0*d0 + d1*d1 + d2*d2 + EPS_VN);
        if (dot < 0.f) {
          ov[i][0][r] = SLOPE_VN*x0 + (1.f-SLOPE_VN)*(x0 - kk*d0);
          ov[i][1][r] = SLOPE_VN*x1 + (1.f-SLOPE_VN)*(x1 - kk*d1);
          ov[i][2][r] = SLOPE_VN*x2 + (1.f-SLOPE_VN)*(x2 - kk*d2);
        }
      }
      for (int c = 0; c < 3; ++c) stCD(sv + c * E * VSTR, VSTR, wv + i * 4, ov[i][c]);
    }
    __syncthreads();
  }

  // ================= g2: linear (128 -> 128) =================
  {
    ffrag vh[2][3];
    #pragma unroll
    for (int i = 0; i < 2; ++i) for (int c = 0; c < 3; ++c) vh[i][c] = zero;
    gemmV<2, 4>(W.g2_Wvh, 128, sv, vh);
    #pragma unroll
    for (int i = 0; i < 2; ++i) {
      const int tile = wv + i * 4;
      for (int c = 0; c < 3; ++c) stCD(svh + c * E * VSTR, VSTR, tile, vh[i][c]);
      ffrag n;
      for (int r = 0; r < 4; ++r)
        n[r] = sqrtf(vh[i][0][r]*vh[i][0][r] + vh[i][1][r]*vh[i][1][r] + vh[i][2][r]*vh[i][2][r]);
      stCD(scat, SSTR, tile, n);
    }
    __syncthreads();

    ffrag so[2]; so[0] = zero; so[1] = zero;
    gemmS<2, 8>(W.g2_Ws, 256, scat, SSTR, so);
    __syncthreads();
    #pragma unroll
    for (int i = 0; i < 2; ++i) {
      stCD(souts, OSTR, wv + i * 4, so[i]);
      stCD(scat + 256, SSTR, wv + i * 4, so[i]);      // s for a1 at [256:384], no act
    }
    __syncthreads();

    ffrag ov[2][3]; ffrag g[2];
    #pragma unroll
    for (int i = 0; i < 2; ++i) { g[i] = zero; for (int c = 0; c < 3; ++c) ov[i][c] = zero; }
    gemmV<2, 4>(W.g2_Wvo, 128, svh, ov);
    gemmS<2, 4>(W.g2_Wg, 128, souts, OSTR, g);
    #pragma unroll
    for (int i = 0; i < 2; ++i) {
      const int tile = wv + i * 4;
      const float4 b = *(const float4*)(W.g2_bg + tile * 16 + q * 4);
      const float bb[4] = {b.x, b.y, b.z, b.w};
      for (int r = 0; r < 4; ++r) {
        float gg = sigm(g[i][r] + bb[r]);
        ov[i][0][r] *= gg; ov[i][1][r] *= gg; ov[i][2][r] *= gg;
      }
      for (int c = 0; c < 3; ++c) stCD(sv + c * E * VSTR, VSTR, tile, ov[i][c]);
    }
    __syncthreads();
  }

  // ================= a1: perceptron (128 -> H=256 -> O=256) =================
  {
    ffrag vh[4][3];
    #pragma unroll
    for (int i = 0; i < 4; ++i) for (int c = 0; c < 3; ++c) vh[i][c] = zero;
    gemmV<4, 4>(W.a1_Wvh, 128, sv, vh);
    #pragma unroll
    for (int i = 0; i < 4; ++i) {
      const int tile = wv + i * 4;
      for (int c = 0; c < 3; ++c) stCD(svh + c * E * VSTR, VSTR, tile, vh[i][c]);
      ffrag n;
      for (int r = 0; r < 4; ++r)
        n[r] = sqrtf(vh[i][0][r]*vh[i][0][r] + vh[i][1][r]*vh[i][1][r] + vh[i][2][r]*vh[i][2][r]);
      stCD(scat, SSTR, tile, n);   // vnorm -> scat[0:256]
    }
    __syncthreads();

    ffrag so[2]; so[0] = zero; so[1] = zero;
    gemmS<2, 12>(W.a1_Ws, 384, scat, SSTR, so);
    __syncthreads();
    #pragma unroll
    for (int i = 0; i < 2; ++i) {
      stCD(souts, OSTR, wv + i * 4, so[i]);
      ffrag l;
      for (int r = 0; r < 4; ++r) { float x = so[i][r]; l[r] = x >= 0.f ? x : SLOPE_SCA * x; }
      stCD(scat + 128, SSTR, wv + i * 4, l);          // s1 for a2 at [128:256]
    }
    __syncthreads();

    ffrag ov[4][3]; ffrag g[4];
    #pragma unroll
    for (int i = 0; i < 4; ++i) { g[i] = zero; for (int c = 0; c < 3; ++c) ov[i][c] = zero; }
    gemmV<4, 8>(W.a1_Wvo, 256, svh, ov);
    gemmS<4, 4>(W.a1_Wg, 128, souts, OSTR, g);
    #pragma unroll
    for (int i = 0; i < 4; ++i) {
      const int tile = wv + i * 4;
      const float4 b = *(const float4*)(W.a1_bg + tile * 16 + q * 4);
      const float bb[4] = {b.x, b.y, b.z, b.w};
      for (int r = 0; r < 4; ++r) {
        float gg = sigm(g[i][r] + bb[r]);
        ov[i][0][r] *= gg; ov[i][1][r] *= gg; ov[i][2][r] *= gg;
      }
      for (int c = 0; c < 3; ++c) stCD(sv + c * E * VSTR, VSTR, tile, ov[i][c]);
    }
    __syncthreads();

    ffrag d[4][3];
    #pragma unroll
    for (int i = 0; i < 4; ++i) for (int c = 0; c < 3; ++c) d[i][c] = zero;
    gemmV<4, 8>(W.a1_Wd, 256, sv, d);
    __syncthreads();
    #pragma unroll
    for (int i = 0; i < 4; ++i) {
      for (int r = 0; r < 4; ++r) {
        float x0 = ov[i][0][r], x1 = ov[i][1][r], x2 = ov[i][2][r];
        float d0 = d[i][0][r],  d1 = d[i][1][r],  d2 = d[i][2][r];
        float dot = x0*d0 + x1*d1 + x2*d2;
        float kk = dot / (d0*d0 + d1*d1 + d2*d2 + EPS_VN);
        if (dot < 0.f) {
          ov[i][0][r] = SLOPE_VN*x0 + (1.f-SLOPE_VN)*(x0 - kk*d0);
          ov[i][1][r] = SLOPE_VN*x1 + (1.f-SLOPE_VN)*(x1 - kk*d1);
          ov[i][2][r] = SLOPE_VN*x2 + (1.f-SLOPE_VN)*(x2 - kk*d2);
        }
      }
      for (int c = 0; c < 3; ++c) stCD(sv + c * E * VSTR, VSTR, wv + i * 4, ov[i][c]);
    }
    __syncthreads();
  }

  // ---- mid: inner[e][h] = <v1[128+h], relpos[e]> -> scat[256:384] ----
  {
    const float r0 = srel[el * 3 + 0], r1 = srel[el * 3 + 1], r2 = srel[el * 3 + 2];
    for (int h = c0; h < 128; h += 16) {
      float x0 = (float)sv[0 * E * VSTR + el * VSTR + 128 + h];
      float x1 = (float)sv[1 * E * VSTR + el * VSTR + 128 + h];
      float x2 = (float)sv[2 * E * VSTR + el * VSTR + 128 + h];
      scat[el * SSTR + 256 + h] = (_Float16)(x0 * r0 + x1 * r1 + x2 * r2);
    }
  }
  // no sync needed yet: a2's vh GEMM only reads sv

  // ================= a2: perceptron (v = v1[:,:128], s2 = [s1, inner]) =========
  {
    ffrag vh[2][3];
    #pragma unroll
    for (int i = 0; i < 2; ++i) for (int c = 0; c < 3; ++c) vh[i][c] = zero;
    gemmV<2, 4>(W.a2_Wvh, 128, sv, vh);
    #pragma unroll
    for (int i = 0; i < 2; ++i) {
      const int tile = wv + i * 4;
      for (int c = 0; c < 3; ++c) stCD(svh + c * E * VSTR, VSTR, tile, vh[i][c]);
      ffrag n;
      for (int r = 0; r < 4; ++r)
        n[r] = sqrtf(vh[i][0][r]*vh[i][0][r] + vh[i][1][r]*vh[i][1][r] + vh[i][2][r]*vh[i][2][r]);
      stCD(scat, SSTR, tile, n);
    }
    __syncthreads();

    ffrag so[2]; so[0] = zero; so[1] = zero;
    gemmS<2, 12>(W.a2_Ws, 384, scat, SSTR, so);
    __syncthreads();
    #pragma unroll
    for (int i = 0; i < 2; ++i) {
      stCD(souts, OSTR, wv + i * 4, so[i]);
      ffrag l;
      for (int r = 0; r < 4; ++r) { float x = so[i][r]; l[r] = x >= 0.f ? x : SLOPE_SCA * x; }
      stCD(scat + 128, SSTR, wv + i * 4, l);          // s_a2 for f at [128:256]
    }
    __syncthreads();

    ffrag ov[2][3]; ffrag g[2];
    #pragma unroll
    for (int i = 0; i < 2; ++i) { g[i] = zero; for (int c = 0; c < 3; ++c) ov[i][c] = zero; }
    gemmV<2, 4>(W.a2_Wvo, 128, svh, ov);
    gemmS<2, 4>(W.a2_Wg, 128, souts, OSTR, g);
    #pragma unroll
    for (int i = 0; i < 2; ++i) {
      const int tile = wv + i * 4;
      const float4 b = *(const float4*)(W.a2_bg + tile * 16 + q * 4);
      const float bb[4] = {b.x, b.y, b.z, b.w};
      for (int r = 0; r < 4; ++r) {
        float gg = sigm(g[i][r] + bb[r]);
        ov[i][0][r] *= gg; ov[i][1][r] *= gg; ov[i][2][r] *= gg;
      }
      for (int c = 0; c < 3; ++c) stCD(sv + c * E * VSTR, VSTR, tile, ov[i][c]);
    }
    __syncthreads();

    ffrag d[2][3];
    #pragma unroll
    for (int i = 0; i < 2; ++i) for (int c = 0; c < 3; ++c) d[i][c] = zero;
    gemmV<2, 4>(W.a2_Wd, 128, sv, d);
    __syncthreads();
    #pragma unroll
    for (int i = 0; i < 2; ++i) {
      for (int r = 0; r < 4; ++r) {
        float x0 = ov[i][0][r], x1 = ov[i][1][r], x2 = ov[i][2][r];
        float d0 = d[i][0][r],  d1 = d[i][1][r],  d2 = d[i][2][r];
        float dot = x0*d0 + x1*d1 + x2*d2;
        float kk = dot / (d0*d0 + d1*d1 + d2*d2 + EPS_VN);
        if (dot < 0.f) {
          ov[i][0][r] = SLOPE_VN*x0 + (1.f-SLOPE_VN)*(x0 - kk*d0);
          ov[i][1][r] = SLOPE_VN*x1 + (1.f-SLOPE_VN)*(x1 - kk*d1);
          ov[i][2][r] = SLOPE_VN*x2 + (1.f-SLOPE_VN)*(x2 - kk*d2);
        }
      }
      for (int c = 0; c < 3; ++c) stCD(sv + c * E * VSTR, VSTR, wv + i * 4, ov[i][c]);
    }
    __syncthreads();
  }

  // ================= f: vnorm + final dot =================
  {
    ffrag vh[2][3];
    #pragma unroll
    for (int i = 0; i < 2; ++i) for (int c = 0; c < 3; ++c) vh[i][c] = zero;
    gemmV<2, 4>(W.f_Wvh, 128, sv, vh);
    #pragma unroll
    for (int i = 0; i < 2; ++i) {
      ffrag n;
      for (int r = 0; r < 4; ++r)
        n[r] = sqrtf(vh[i][0][r]*vh[i][0][r] + vh[i][1][r]*vh[i][1][r] + vh[i][2][r]*vh[i][2][r]);
      stCD(scat, SSTR, wv + i * 4, n);
    }
    __syncthreads();

    float part = 0.f;
    for (int c = c0; c < 256; c += 16)
      part += (float)scat[el * SSTR + c] * W.f_Ws[c];
    part += __shfl_xor(part, 8, 16);
    part += __shfl_xor(part, 4, 16);
    part += __shfl_xor(part, 2, 16);
    part += __shfl_xor(part, 1, 16);
    if (c0 == 0 && eg < F) out[eg] = part;
  }
}

extern "C" void kernel_launch(void* const* d_in, const int* in_sizes, int n_in,
                              void* d_out, int out_size, void* d_ws, size_t ws_size,
                              hipStream_t stream) {
  const float* h_sca       = (const float*)d_in[0];
  const float* h_vec       = (const float*)d_in[1];
  const float* pos_compose = (const float*)d_in[2];
  const float* pos         = (const float*)d_in[3];
  const int* idx_focal     = (const int*)d_in[29];
  const int F = in_sizes[29];

  // weight conversion jobs: d_in index -> packed f16 in d_ws
  const int widx[20] = {4,5,6,7,9, 10,11,12,13, 15,16,17,18,20, 21,22,23,24,26, 27};
  CvtJobs J;
  _Float16* wsp = (_Float16*)d_ws;
  size_t off = 0;
  const _Float16* wptr[20];
  for (int j = 0; j < 20; ++j) {
    J.src[j] = (const float*)d_in[widx[j]];
    J.dst[j] = wsp + off;
    J.n[j]   = in_sizes[widx[j]];
    wptr[j]  = wsp + off;
    off += in_sizes[widx[j]];
  }
  cvt_kernel<<<dim3(32, 20), dim3(256), 0, stream>>>(J);

  WB W;
  W.g1_Wvh = wptr[0];  W.g1_Ws = wptr[1];  W.g1_Wvo = wptr[2];  W.g1_Wg = wptr[3];  W.g1_Wd = wptr[4];
  W.g2_Wvh = wptr[5];  W.g2_Ws = wptr[6];  W.g2_Wvo = wptr[7];  W.g2_Wg = wptr[8];
  W.a1_Wvh = wptr[9];  W.a1_Ws = wptr[10]; W.a1_Wvo = wptr[11]; W.a1_Wg = wptr[12]; W.a1_Wd = wptr[13];
  W.a2_Wvh = wptr[14]; W.a2_Ws = wptr[15]; W.a2_Wvo = wptr[16]; W.a2_Wg = wptr[17]; W.a2_Wd = wptr[18];
  W.f_Wvh  = wptr[19];
  W.g1_bg = (const float*)d_in[8];
  W.g2_bg = (const float*)d_in[14];
  W.a1_bg = (const float*)d_in[19];
  W.a2_bg = (const float*)d_in[25];
  W.f_Ws  = (const float*)d_in[28];

  const int blocks = (F + E - 1) / E;
  pe_kernel<<<dim3(blocks), dim3(TPB), 0, stream>>>(
      h_sca, h_vec, pos_compose, pos, W, idx_focal, (float*)d_out, F);
}